// Round 3
// baseline (1017.173 us; speedup 1.0000x reference)
//
#include <hip/hip_runtime.h>
#include <cstdint>

typedef unsigned short u16;
typedef __bf16 bf16_t;
typedef bf16_t bf16x8 __attribute__((ext_vector_type(8)));
typedef float f32x4 __attribute__((ext_vector_type(4)));

#define B_ 4
#define S_ 1024
#define D_ 1024
#define E_ 8
#define R_ 8
#define H_ 16
#define DH_ 64

static __device__ __forceinline__ u16 f2b(float f){
    union { float f; uint32_t i; } v; v.f = f;
    uint32_t i = v.i;
    uint32_t r = i + 0x7FFFu + ((i >> 16) & 1u);   // RNE
    return (u16)(r >> 16);
}

// ---------------- fp32 -> bf16 convert ----------------
__global__ void k_cvt(const float* src, u16* dst, int n){
    for (int i = blockIdx.x*blockDim.x + threadIdx.x; i < n; i += gridDim.x*blockDim.x)
        dst[i] = f2b(src[i]);
}

// ---------------- router: cw_pool + const term ----------------
__global__ void k_cwp(const float* conv_w, const float* conv_b, const float* pool_w,
                      const float* pool_b, float* cwp, float* constk){
    __shared__ float red[256];
    int bid = blockIdx.x;
    if (bid < 12){
        int j = bid*256 + threadIdx.x;       // j = t*1024 + i
        int t = j >> 10, i = j & 1023;
        float acc = 0.f;
        for (int o = 0; o < D_; ++o)
            acc += pool_w[o] * conv_w[(size_t)o*3072 + i*3 + t];
        cwp[j] = acc;
    } else {
        float acc = 0.f;
        for (int o = threadIdx.x; o < D_; o += 256) acc += pool_w[o] * conv_b[o];
        red[threadIdx.x] = acc; __syncthreads();
        for (int s = 128; s > 0; s >>= 1){
            if (threadIdx.x < s) red[threadIdx.x] += red[threadIdx.x+s];
            __syncthreads();
        }
        if (threadIdx.x == 0) *constk = red[0] + pool_b[0];
    }
}

// ---------------- router: scores[b,s] ----------------
__global__ void k_scores(const float* x, const float* cwp, const float* constk, float* scores){
    int s = blockIdx.x, b = blockIdx.y;
    const float* xb = x + (size_t)b*S_*D_;
    float acc = 0.f;
    for (int j = threadIdx.x; j < 3*D_; j += 256){
        int t = j >> 10, i = j & 1023;
        int sm = s + t - 1;
        if (sm >= 0 && sm < S_) acc += xb[(size_t)sm*D_ + i] * cwp[j];
    }
    __shared__ float red[256];
    red[threadIdx.x] = acc; __syncthreads();
    for (int st = 128; st > 0; st >>= 1){
        if (threadIdx.x < st) red[threadIdx.x] += red[threadIdx.x+st];
        __syncthreads();
    }
    if (threadIdx.x == 0) scores[b*S_ + s] = red[0] + *constk;
}

// ---------------- router: softmax over seq ----------------
__global__ void k_softw(const float* scores, float* wsm){
    int b = blockIdx.x;
    __shared__ float red[256];
    float mx = -1e30f;
    for (int s = threadIdx.x; s < S_; s += 256) mx = fmaxf(mx, scores[b*S_+s]);
    red[threadIdx.x] = mx; __syncthreads();
    for (int st = 128; st > 0; st >>= 1){
        if (threadIdx.x < st) red[threadIdx.x] = fmaxf(red[threadIdx.x], red[threadIdx.x+st]);
        __syncthreads();
    }
    mx = red[0]; __syncthreads();
    float sum = 0.f;
    for (int s = threadIdx.x; s < S_; s += 256) sum += expf(scores[b*S_+s] - mx);
    red[threadIdx.x] = sum; __syncthreads();
    for (int st = 128; st > 0; st >>= 1){
        if (threadIdx.x < st) red[threadIdx.x] += red[threadIdx.x+st];
        __syncthreads();
    }
    float inv = 1.f / red[0];
    for (int s = threadIdx.x; s < S_; s += 256)
        wsm[b*S_+s] = expf(scores[b*S_+s] - mx) * inv;
}

// ---------------- router: xw[b][i*3+t] = sum_s w[s] x[b,s+t-1,i] ----------------
__global__ void k_xw(const float* x, const float* wsm, float* xwl){
    int b = blockIdx.y;
    int i = blockIdx.x*64 + threadIdx.x;
    const float* xb = x + (size_t)b*S_*D_;
    float a0 = 0.f, a1 = 0.f, a2 = 0.f;
    for (int r = 0; r < S_; ++r){
        float xv = xb[(size_t)r*D_ + i];
        float w1 = wsm[b*S_ + r];
        float w0 = (r+1 < S_) ? wsm[b*S_ + r + 1] : 0.f;
        float w2 = (r >= 1)   ? wsm[b*S_ + r - 1] : 0.f;
        a0 += w0*xv; a1 += w1*xv; a2 += w2*xv;
    }
    xwl[b*3072 + i*3 + 0] = a0;
    xwl[b*3072 + i*3 + 1] = a1;
    xwl[b*3072 + i*3 + 2] = a2;
}

// ---------------- router: pooled[b,o] ----------------
__global__ void k_pooled(const float* conv_w, const float* conv_b, const float* xwl, float* pooled){
    int o = blockIdx.x*4 + (threadIdx.x >> 6);
    int lane = threadIdx.x & 63;
    const float* cw = conv_w + (size_t)o*3072;
    float a0=0.f, a1=0.f, a2=0.f, a3=0.f;
    for (int j = lane; j < 3072; j += 64){
        float c = cw[j];
        a0 += c*xwl[j]; a1 += c*xwl[3072+j]; a2 += c*xwl[2*3072+j]; a3 += c*xwl[3*3072+j];
    }
    for (int off = 32; off; off >>= 1){
        a0 += __shfl_down(a0, off); a1 += __shfl_down(a1, off);
        a2 += __shfl_down(a2, off); a3 += __shfl_down(a3, off);
    }
    if (lane == 0){
        float cb = conv_b[o];
        pooled[0*D_+o] = a0+cb; pooled[1*D_+o] = a1+cb;
        pooled[2*D_+o] = a2+cb; pooled[3*D_+o] = a3+cb;
    }
}

// ---------------- router: logits + softmax -> route[b,e] ----------------
__global__ void k_route(const float* pooled, const float* rlin_w, const float* rlin_b, float* route){
    __shared__ float lg[B_][E_];
    int t = threadIdx.x;
    int b = t >> 6, e = (t >> 3) & 7, part = t & 7;
    float acc = 0.f;
    for (int o = part; o < D_; o += 8) acc += pooled[b*D_+o] * rlin_w[e*D_+o];
    acc += __shfl_down(acc, 4); acc += __shfl_down(acc, 2); acc += __shfl_down(acc, 1);
    if (part == 0) lg[b][e] = acc + rlin_b[e];
    __syncthreads();
    if (t < B_){
        float mx = -1e30f;
        for (int e2 = 0; e2 < E_; ++e2) mx = fmaxf(mx, lg[t][e2]);
        float ex[E_], sum = 0.f;
        for (int e2 = 0; e2 < E_; ++e2){ ex[e2] = expf(lg[t][e2]-mx); sum += ex[e2]; }
        for (int e2 = 0; e2 < E_; ++e2) route[t*E_+e2] = ex[e2]/sum;
    }
}

// ---------------- AeffT[z][d][k] = 2*route[b,e]*A_p[e,r,d], k=e*8+r ----------------
__global__ void k_aeff(const float* qA, const float* kA, const float* vA, const float* oA,
                       const float* route, u16* AeffT){
    int dc = blockIdx.x, b = blockIdx.y, p = blockIdx.z;
    const float* Ap = (p==0)?qA:(p==1)?kA:(p==2)?vA:oA;
    int z = p*4 + b;
    for (int idx = threadIdx.x; idx < 64*64; idx += 256){
        int dl = idx >> 6, kk = idx & 63;
        int d = dc*64 + dl;
        int e = kk >> 3, r = kk & 7;
        float v = 2.0f * route[b*E_+e] * Ap[(size_t)(e*R_+r)*D_ + d];
        AeffT[((size_t)z*D_ + d)*64 + kk] = f2b(v);
    }
}

// ---------------- Weff[z][n][d] = W_p[n,d] + Bfold[n,:] @ AeffT[:,d]  (K=64 MFMA) ----------------
__global__ __launch_bounds__(256) void k_weff(
        const u16* B16,                       // bf16 copies of q/k/v/o B, each 64K elems
        const float* qW, const float* kW, const float* vW, const float* oW,
        const u16* AeffT, u16* Weff){
    __shared__ __align__(16) u16 As[128*64];
    __shared__ __align__(16) u16 Bs[128*64];
    int z = blockIdx.z, p = z >> 2;
    const u16* Bp = B16 + (size_t)p*E_*D_*R_;
    const float* Wp = (p==0)?qW:(p==1)?kW:(p==2)?vW:oW;
    int n0 = blockIdx.x*128, d0 = blockIdx.y*128;
    int tid = threadIdx.x;
    int e = tid & 7, row = tid >> 3;
    for (int pass = 0; pass < 4; ++pass){
        int rr = row + pass*32;
        *(uint4*)&As[rr*64 + e*8] = *(const uint4*)&Bp[((size_t)e*D_ + (n0+rr))*R_];
        *(uint4*)&Bs[rr*64 + e*8] = *(const uint4*)&AeffT[((size_t)z*D_ + (d0+rr))*64 + e*8];
    }
    __syncthreads();
    int l = tid & 63, w = tid >> 6;
    int wm = (w & 1)*64, wn = (w >> 1)*64;
    int lr = l & 15, quad = l >> 4;
    f32x4 acc[4][4] = {};
    for (int kk = 0; kk < 64; kk += 32){
        bf16x8 af[4], bg[4];
        for (int i = 0; i < 4; ++i) af[i] = *(const bf16x8*)&As[(wm + i*16 + lr)*64 + kk + quad*8];
        for (int j = 0; j < 4; ++j) bg[j] = *(const bf16x8*)&Bs[(wn + j*16 + lr)*64 + kk + quad*8];
        for (int i = 0; i < 4; ++i)
            for (int j = 0; j < 4; ++j)
                acc[i][j] = __builtin_amdgcn_mfma_f32_16x16x32_bf16(af[i], bg[j], acc[i][j], 0, 0, 0);
    }
    u16* Wz = Weff + (size_t)z*D_*D_;
    for (int i = 0; i < 4; ++i)
        for (int j = 0; j < 4; ++j)
            for (int r2 = 0; r2 < 4; ++r2){
                int n = n0 + wm + i*16 + quad*4 + r2;
                int d = d0 + wn + j*16 + lr;
                Wz[(size_t)n*D_ + d] = f2b(acc[i][j][r2] + Wp[(size_t)n*D_ + d]);
            }
}

// ---------------- generic 128x128 MFMA GEMM ----------------
// C[m,n] = scale*(sum_k A[m,k]*Bw[n,k] + bias[n]);  writes bf16 (Cb) or fp32 (Cf)
__global__ __launch_bounds__(256) void k_gemm(
        const u16* A, long long strideA, int lda,
        const u16* Bw, long long strideB,
        u16* Cb, float* Cf, long long strideC, int ldc,
        const float* bias, float scale, int K){
    __shared__ __align__(16) u16 As[128*32];
    __shared__ __align__(16) u16 Bs[128*32];
    int zb = blockIdx.z;
    A += (size_t)zb*strideA; Bw += (size_t)zb*strideB;
    if (Cf) Cf += (size_t)zb*strideC; else Cb += (size_t)zb*strideC;
    int m0 = blockIdx.x*128, n0 = blockIdx.y*128;
    int tid = threadIdx.x;
    int srow = tid >> 2, skc = (tid & 3)*8;
    int l = tid & 63, w = tid >> 6;
    int wm = (w & 1)*64, wn = (w >> 1)*64;
    int lr = l & 15, quad = l >> 4;
    f32x4 acc[4][4] = {};
    for (int k0 = 0; k0 < K; k0 += 32){
        __syncthreads();
        *(uint4*)&As[srow*32 + skc]        = *(const uint4*)&A[(size_t)(m0+srow)*lda + k0 + skc];
        *(uint4*)&As[(srow+64)*32 + skc]   = *(const uint4*)&A[(size_t)(m0+srow+64)*lda + k0 + skc];
        *(uint4*)&Bs[srow*32 + skc]        = *(const uint4*)&Bw[(size_t)(n0+srow)*D_ + k0 + skc];
        *(uint4*)&Bs[(srow+64)*32 + skc]   = *(const uint4*)&Bw[(size_t)(n0+srow+64)*D_ + k0 + skc];
        __syncthreads();
        bf16x8 af[4], bg[4];
        for (int i = 0; i < 4; ++i) af[i] = *(const bf16x8*)&As[(wm + i*16 + lr)*32 + quad*8];
        for (int j = 0; j < 4; ++j) bg[j] = *(const bf16x8*)&Bs[(wn + j*16 + lr)*32 + quad*8];
        for (int i = 0; i < 4; ++i)
            for (int j = 0; j < 4; ++j)
                acc[i][j] = __builtin_amdgcn_mfma_f32_16x16x32_bf16(af[i], bg[j], acc[i][j], 0, 0, 0);
    }
    for (int j = 0; j < 4; ++j){
        int n = n0 + wn + j*16 + lr;
        float bv = bias ? bias[n] : 0.f;
        for (int i = 0; i < 4; ++i){
            int mrow = m0 + wm + i*16 + quad*4;
            for (int r2 = 0; r2 < 4; ++r2){
                float val = (acc[i][j][r2] + bv) * scale;
                size_t idx = (size_t)(mrow+r2)*ldc + n;
                if (Cf) Cf[idx] = val; else Cb[idx] = f2b(val);
            }
        }
    }
}

// ---------------- v -> vT[b][h][d][s] ----------------
__global__ void k_vtrans(const u16* v, u16* vT){
    __shared__ __align__(16) u16 Tl[64*72];
    int st = blockIdx.x, bh = blockIdx.y;
    int b = bh >> 4, h = bh & 15;
    int tid = threadIdx.x;
    int row = tid >> 3, c = (tid & 7)*8;
    const u16* vb = v + (size_t)b*S_*D_ + h*64;
    for (int pass = 0; pass < 2; ++pass){
        int r = row + pass*32;
        *(uint4*)&Tl[r*72 + c] = *(const uint4*)&vb[(size_t)(st*64 + r)*D_ + c];
    }
    __syncthreads();
    u16* vTb = vT + (size_t)bh*64*S_;
    for (int pass = 0; pass < 2; ++pass){
        int dr = row + pass*32;
        union { u16 s[8]; uint4 u; } tmp;
        for (int j = 0; j < 8; ++j) tmp.s[j] = Tl[(c+j)*72 + dr];
        *(uint4*)&vTb[(size_t)dr*S_ + st*64 + c] = tmp.u;
    }
}

// ---------------- fused attention: writes qk (fp32) + wv (bf16) ----------------
__global__ __launch_bounds__(256) void k_attn(const u16* q, const u16* k, const u16* vT,
                                              float* qk_out, u16* wv){
    __shared__ __align__(16) u16 Ql[64*72];
    __shared__ __align__(16) u16 Kl[64*72];
    __shared__ __align__(16) u16 Vt[64*72];
    __shared__ __align__(16) u16 Pl[64*72];
    int qt = blockIdx.x, bh = blockIdx.y;
    int b = bh >> 4, h = bh & 15;
    int q0 = qt*64;
    int tid = threadIdx.x;
    int row = tid >> 3, c = (tid & 7)*8;
    int l = tid & 63, w = tid >> 6;
    int lr = l & 15, quad = l >> 4;
    const u16* qp  = q  + (size_t)b*S_*D_ + h*64;
    const u16* kp  = k  + (size_t)b*S_*D_ + h*64;
    const u16* vTp = vT + (size_t)bh*64*S_;
    float* qko = qk_out + (size_t)bh*S_*S_;
    for (int pass = 0; pass < 2; ++pass){
        int r = row + pass*32;
        *(uint4*)&Ql[r*72 + c] = *(const uint4*)&qp[(size_t)(q0 + r)*D_ + c];
    }
    f32x4 oacc[4] = {};
    float m_i[4], l_i[4];
    for (int r2 = 0; r2 < 4; ++r2){ m_i[r2] = -1e30f; l_i[r2] = 0.f; }
    for (int t0 = 0; t0 < S_; t0 += 64){
        __syncthreads();
        for (int pass = 0; pass < 2; ++pass){
            int r = row + pass*32;
            *(uint4*)&Kl[r*72 + c] = *(const uint4*)&kp[(size_t)(t0 + r)*D_ + c];
            *(uint4*)&Vt[r*72 + c] = *(const uint4*)&vTp[(size_t)r*S_ + t0 + c];
        }
        __syncthreads();
        // S = Q K^T  (wave w: q-rows w*16..w*16+15, all 64 t of this tile)
        f32x4 sacc[4] = {};
        for (int kk = 0; kk < 64; kk += 32){
            bf16x8 aq = *(const bf16x8*)&Ql[(w*16 + lr)*72 + kk + quad*8];
            for (int jn = 0; jn < 4; ++jn){
                bf16x8 bk = *(const bf16x8*)&Kl[(jn*16 + lr)*72 + kk + quad*8];
                sacc[jn] = __builtin_amdgcn_mfma_f32_16x16x32_bf16(aq, bk, sacc[jn], 0, 0, 0);
            }
        }
        // write raw scores (pre-softmax) as fp32
        for (int jn = 0; jn < 4; ++jn)
            for (int r2 = 0; r2 < 4; ++r2){
                int sq = q0 + w*16 + quad*4 + r2;
                qko[(size_t)sq*S_ + t0 + jn*16 + lr] = sacc[jn][r2];
            }
        // online softmax (fp32, from fp32 scores)
        float alpha[4];
        for (int r2 = 0; r2 < 4; ++r2){
            float mx = fmaxf(fmaxf(sacc[0][r2], sacc[1][r2]), fmaxf(sacc[2][r2], sacc[3][r2]));
            for (int off = 1; off < 16; off <<= 1) mx = fmaxf(mx, __shfl_xor(mx, off));
            float mnew = fmaxf(m_i[r2], mx);
            alpha[r2] = expf(m_i[r2] - mnew);
            m_i[r2] = mnew;
        }
        f32x4 p[4];
        for (int jn = 0; jn < 4; ++jn)
            for (int r2 = 0; r2 < 4; ++r2)
                p[jn][r2] = expf(sacc[jn][r2] - m_i[r2]);
        for (int r2 = 0; r2 < 4; ++r2){
            float s = p[0][r2] + p[1][r2] + p[2][r2] + p[3][r2];
            for (int off = 1; off < 16; off <<= 1) s += __shfl_xor(s, off);
            l_i[r2] = l_i[r2]*alpha[r2] + s;
        }
        for (int jn = 0; jn < 4; ++jn)
            for (int r2 = 0; r2 < 4; ++r2)
                oacc[jn][r2] *= alpha[r2];
        // P: C/D layout -> LDS -> A layout
        for (int jn = 0; jn < 4; ++jn)
            for (int r2 = 0; r2 < 4; ++r2)
                Pl[(w*16 + quad*4 + r2)*72 + jn*16 + lr] = f2b(p[jn][r2]);
        __syncthreads();
        // O += P V
        for (int kk = 0; kk < 64; kk += 32){
            bf16x8 ap = *(const bf16x8*)&Pl[(w*16 + lr)*72 + kk + quad*8];
            for (int jn = 0; jn < 4; ++jn){
                bf16x8 bv = *(const bf16x8*)&Vt[(jn*16 + lr)*72 + kk + quad*8];
                oacc[jn] = __builtin_amdgcn_mfma_f32_16x16x32_bf16(ap, bv, oacc[jn], 0, 0, 0);
            }
        }
    }
    u16* wvp = wv + (size_t)b*S_*D_ + h*64;
    for (int r2 = 0; r2 < 4; ++r2){
        float inv = 1.f / l_i[r2];
        int sq = q0 + w*16 + quad*4 + r2;
        for (int jn = 0; jn < 4; ++jn)
            wvp[(size_t)sq*D_ + jn*16 + lr] = f2b(oacc[jn][r2] * inv);
    }
}

extern "C" void kernel_launch(void* const* d_in, const int* in_sizes, int n_in,
                              void* d_out, int out_size, void* d_ws, size_t ws_size,
                              hipStream_t stream){
    const float* x      = (const float*)d_in[0];
    const float* conv_w = (const float*)d_in[1];
    const float* conv_b = (const float*)d_in[2];
    const float* pool_w = (const float*)d_in[3];
    const float* pool_b = (const float*)d_in[4];
    const float* rlin_w = (const float*)d_in[5];
    const float* rlin_b = (const float*)d_in[6];
    const float* qW = (const float*)d_in[7];
    const float* qb = (const float*)d_in[8];
    const float* qA = (const float*)d_in[9];
    const float* qB = (const float*)d_in[10];
    const float* kW = (const float*)d_in[11];
    const float* kA = (const float*)d_in[12];
    const float* kB = (const float*)d_in[13];
    const float* vW = (const float*)d_in[14];
    const float* vb = (const float*)d_in[15];
    const float* vA = (const float*)d_in[16];
    const float* vB = (const float*)d_in[17];
    const float* oW = (const float*)d_in[18];
    const float* ob = (const float*)d_in[19];
    const float* oA = (const float*)d_in[20];
    const float* oB = (const float*)d_in[21];

    char* ws = (char*)d_ws;
    float* route  = (float*)(ws + 0);
    float* scores = (float*)(ws + 1024);
    float* wsm    = (float*)(ws + 20480);
    float* xwl    = (float*)(ws + 40960);
    float* pooled = (float*)(ws + 102400);
    float* cwp    = (float*)(ws + 131072);
    float* constk = (float*)(ws + 143360);
    u16* AeffT = (u16*)(ws + (1ull  << 20));                 // 2 MB
    u16* B16   = (u16*)(ws + (3ull  << 20));                 // 512 KB (q,k,v,o B)
    u16* Weff  = (u16*)(ws + (4ull  << 20));                 // 32 MB
    u16* x16   = (u16*)(ws + (36ull << 20));                 // 8 MB
    u16* qbuf  = (u16*)(ws + (44ull << 20));                 // 8 MB
    u16* kbuf  = (u16*)(ws + (52ull << 20));                 // 8 MB
    u16* vbuf  = (u16*)(ws + (60ull << 20));                 // 8 MB (reused as wv)
    u16* vTbuf = (u16*)(ws + (68ull << 20));                 // 8 MB  -> total 76 MB
    u16* wvbuf = vbuf;                                       // v dead after k_vtrans

    float* out    = (float*)d_out;
    float* qk_out = out + (size_t)B_*S_*D_;

    const long long sSD = (long long)S_*D_;
    const long long sDD = (long long)D_*D_;
    const float SC = 0.35355339059327373f;   // 64^-0.25

    // fp32 -> bf16 copies
    k_cvt<<<4096, 256, 0, stream>>>(x, x16, B_*S_*D_);
    k_cvt<<<64, 256, 0, stream>>>(qB, B16 + 0*E_*D_*R_, E_*D_*R_);
    k_cvt<<<64, 256, 0, stream>>>(kB, B16 + 1*E_*D_*R_, E_*D_*R_);
    k_cvt<<<64, 256, 0, stream>>>(vB, B16 + 2*E_*D_*R_, E_*D_*R_);
    k_cvt<<<64, 256, 0, stream>>>(oB, B16 + 3*E_*D_*R_, E_*D_*R_);

    k_cwp   <<<13, 256, 0, stream>>>(conv_w, conv_b, pool_w, pool_b, cwp, constk);
    k_scores<<<dim3(S_, B_), 256, 0, stream>>>(x, cwp, constk, scores);
    k_softw <<<B_, 256, 0, stream>>>(scores, wsm);
    k_xw    <<<dim3(16, B_), 64, 0, stream>>>(x, wsm, xwl);
    k_pooled<<<256, 256, 0, stream>>>(conv_w, conv_b, xwl, pooled);
    k_route <<<1, 256, 0, stream>>>(pooled, rlin_w, rlin_b, route);
    k_aeff  <<<dim3(16, B_, 4), 256, 0, stream>>>(qA, kA, vA, oA, route, AeffT);
    k_weff  <<<dim3(8, 8, 16), 256, 0, stream>>>(B16, qW, kW, vW, oW, AeffT, Weff);

    k_gemm<<<dim3(8,8,B_), 256, 0, stream>>>(x16, sSD, D_, Weff + 0*sDD, sDD,
                                             qbuf, (float*)nullptr, sSD, D_, qb, SC, 1024);
    k_gemm<<<dim3(8,8,B_), 256, 0, stream>>>(x16, sSD, D_, Weff + 4*sDD, sDD,
                                             kbuf, (float*)nullptr, sSD, D_, (const float*)nullptr, SC, 1024);
    k_gemm<<<dim3(8,8,B_), 256, 0, stream>>>(x16, sSD, D_, Weff + 8*sDD, sDD,
                                             vbuf, (float*)nullptr, sSD, D_, vb, 1.0f, 1024);
    k_vtrans<<<dim3(16, B_*H_), 256, 0, stream>>>(vbuf, vTbuf);
    k_attn  <<<dim3(16, B_*H_), 256, 0, stream>>>(qbuf, kbuf, vTbuf, qk_out, wvbuf);
    k_gemm<<<dim3(8,8,B_), 256, 0, stream>>>(wvbuf, sSD, D_, Weff + 12*sDD, sDD,
                                             (u16*)nullptr, out, sSD, D_, ob, 1.0f, 1024);
}